// Round 4
// baseline (121.371 us; speedup 1.0000x reference)
//
#include <hip/hip_runtime.h>

// Guided filter r=5, B=8 C=3 H=W=512 fp32 — single fused kernel, round 11.
// TY=16 (grid 8x32x24 = 6144 blocks). All LDS accesses affine (base +
// compile-time immediate; chunk starts multiples of 8 so PB(c0+d) = PB(c0)
// + OFFD(d)).
// Changes vs r10 (all VALU wave-op reductions; layouts/numerics unchanged):
//  - P1: 2 segments of 13 rows (168 thr) instead of 3x9 (252 thr): per-col
//    loads+products 57 -> 46 (-19%), wave-instrs -18%. Unconditional 13-row
//    write loop.
//  - P1 boundary: block-uniform rows_ok test; column-edge blocks take a
//    fast path (plain loads for valid lanes, zero-fill for OOB lanes);
//    full per-row masking only for by in {0,31}.
//  - P2a: static-trip-count split (ch<8 -> 8-loop, ch==8 -> 10-loop;
//    removes runtime `i<nout` mask) x interior/boundary split (interior
//    runs guard-free with inv=1/121).
//  - P2b: same static split for writes.
//  - P4: interior/boundary split (interior: inv const, no ccnt).
// Pipeline: P1 vsums(x,y,xy,xx)->v4[26][97sw] f4 | P2a hsums+A,b->regs |
//   x-prefetch (tid<128) | P2b regs->ab2 (ALIASES v4) | P3 vsums(A,b)->vab
//   @+17,280 | P4 hsums+epilogue, 2x float4 stores.
// Bank floors (words mod 32): all phases at the multi-word access floor
// (b128: 8 words/bank, b64: 4/bank) — measured SQ_LDS_BANK_CONFLICT is
// dominated by this floor, not fixable conflicts.
// ab2 @0, vab @17,280 (=135*128). LDS 40,352 B -> 4 blocks/CU.

#define R    5
#define TX   64
#define TY   16
#define IMG  512
#define AROWS (TY + 2 * R)   // 26
#define ACOLS (TX + 2 * R)   // 74
#define XCOLS (TX + 4 * R)   // 84
#define V4STR 97             // float4 row stride
#define ABSTR 83             // float2 row stride
#define OFF_VAB 17280                            // 135*128 >= ab2's 17,264
#define SMEM_TOTAL (AROWS * V4STR * 16)          // 40,352

#define PB(c)   ((c) + ((c) >> 3))
#define OFFD(d) ((d) + ((d) >> 3))   // PB(c0+d)-PB(c0) when c0%8==0

__device__ __forceinline__ float ccnt(int g) {
    int lo = max(g - R, 0), hi = min(g + R, IMG - 1);
    return (float)(hi - lo + 1);
}

// P2a inner: horizontal 11-sum ring + A,b math. NOUT/INTR compile-time.
template <int NOUT, bool INTR>
__device__ __forceinline__ void p2_body(const float4* __restrict__ bp,
                                        float2* pres, int ax0, float cy,
                                        bool ayok) {
    float4 ring[10];
#pragma unroll
    for (int d = 0; d < 10; ++d) ring[d] = bp[OFFD(d)];
    float sx = 0.f, sy = 0.f, sxy = 0.f, sxx = 0.f;
#pragma unroll
    for (int d = 0; d < 10; ++d) {
        sx += ring[d].x; sy += ring[d].y;
        sxy += ring[d].z; sxx += ring[d].w;
    }
#pragma unroll
    for (int i = 0; i < NOUT; ++i) {
        float4 lead = bp[OFFD(10 + i)];
        sx += lead.x; sy += lead.y; sxy += lead.z; sxx += lead.w;
        if (i > 0) {
            float4 o = ring[i - 1];
            sx -= o.x; sy -= o.y; sxy -= o.z; sxx -= o.w;
        }
        float A = 0.f, bb = 0.f;
        if (INTR) {
            const float inv = 1.0f / 121.0f;
            float mx = sx * inv, my = sy * inv;
            float cov = sxy * inv - mx * my;
            float var = sxx * inv - mx * mx;
            A = cov * __builtin_amdgcn_rcpf(var + 0.01f);
            bb = my - A * mx;
        } else {
            const int ax = ax0 + i;
            if (ayok && ((unsigned)ax < (unsigned)IMG)) {
                float inv = __builtin_amdgcn_rcpf(cy * ccnt(ax));
                float mx = sx * inv, my = sy * inv;
                float cov = sxy * inv - mx * my;
                float var = sxx * inv - mx * mx;
                A = cov * __builtin_amdgcn_rcpf(var + 0.01f);
                bb = my - A * mx;
            }
        }
        pres[i] = make_float2(A, bb);
    }
}

__global__ __launch_bounds__(256, 4) void guided_fused(
        const float* __restrict__ x, const float* __restrict__ y,
        float* __restrict__ out) {
    __shared__ __align__(16) unsigned char smem[SMEM_TOTAL];
    float4 (*v4)[V4STR] = (float4(*)[V4STR])smem;
    float2 (*ab2)[ABSTR] = (float2(*)[ABSTR])smem;              // aliases v4
    float2 (*vab)[ABSTR] = (float2(*)[ABSTR])(smem + OFF_VAB);  // disjoint from ab2

    const int plane = blockIdx.z;
    const int tx0 = blockIdx.x * TX;
    const int ty0 = blockIdx.y * TY;
    const int tid = threadIdx.x;
    const size_t pbase = (size_t)plane * IMG * IMG;
    const float* xp = x + pbase;
    const float* yp = y + pbase;
    const bool interior = (tx0 >= 2 * R) && (tx0 + TX + 2 * R - 1 < IMG) &&
                          (ty0 >= 2 * R) && (ty0 + TY + 2 * R - 1 < IMG);

    // ---- P1: vertical 11-sums at 84 cols x 26 A,b-rows. 2 segs x 13 rows.
    if (tid < 2 * XCOLS) {
        const int seg = (tid >= XCOLS) ? 1 : 0;
        const int cc  = tid - seg * XCOLS;
        const int r0  = seg * 13;             // 0, 13
        const int gx  = tx0 - 2 * R + cc;
        const int gy0 = ty0 - 2 * R + r0;

        float xv[23], yv[23];
        if (interior) {
            const float* xc = xp + (size_t)gy0 * IMG + gx;
            const float* yc = yp + (size_t)gy0 * IMG + gx;
#pragma unroll
            for (int j = 0; j < 23; ++j) {
                xv[j] = xc[(size_t)j * IMG];
                yv[j] = yc[(size_t)j * IMG];
            }
        } else {
            const bool xok = ((unsigned)gx < (unsigned)IMG);
            const bool rows_ok = (gy0 >= 0) && (gy0 + 22 < IMG);
            if (rows_ok) {
                if (xok) {
                    const float* xc = xp + (size_t)gy0 * IMG + gx;
                    const float* yc = yp + (size_t)gy0 * IMG + gx;
#pragma unroll
                    for (int j = 0; j < 23; ++j) {
                        xv[j] = xc[(size_t)j * IMG];
                        yv[j] = yc[(size_t)j * IMG];
                    }
                } else {
#pragma unroll
                    for (int j = 0; j < 23; ++j) { xv[j] = 0.f; yv[j] = 0.f; }
                }
            } else {
#pragma unroll
                for (int j = 0; j < 23; ++j) {
                    int gy = gy0 + j;
                    bool ok = xok && ((unsigned)gy < (unsigned)IMG);
                    size_t o = (size_t)gy * IMG + gx;
                    xv[j] = ok ? xp[o] : 0.f;
                    yv[j] = ok ? yp[o] : 0.f;
                }
            }
        }
        float sx = 0.f, sy = 0.f, sxy = 0.f, sxx = 0.f;
#pragma unroll
        for (int j = 0; j < 11; ++j) {
            sx += xv[j]; sy += yv[j];
            sxy += xv[j] * yv[j]; sxx += xv[j] * xv[j];
        }
        float4* wp = &v4[r0][PB(cc)];
        wp[0] = make_float4(sx, sy, sxy, sxx);
#pragma unroll
        for (int s = 1; s < 13; ++s) {
            float xn = xv[s + 10], yn = yv[s + 10];
            float xo = xv[s - 1],  yo = yv[s - 1];
            sx  += xn - xo;
            sy  += yn - yo;
            sxy += xn * yn - xo * yo;
            sxx += xn * xn - xo * xo;
            wp[(size_t)s * V4STR] = make_float4(sx, sy, sxy, sxx);
        }
    }
    __syncthreads();

    // ---- P2a: horizontal 11-sums -> A,b on 74x26, DEFERRED to registers.
    // 234 threads: chunk ch = tid/26 (0..8), row r = tid%26, c0 = 8ch.
    // Static-trip loops: ch<8 width 8, ch==8 width 10 (cols 64..73).
    int p2_r = 0, p2_pb0 = 0;
    float2 pres[10];
    if (tid < 9 * AROWS) {
        const int ch = tid / AROWS;
        const int r  = tid - ch * AROWS;
        p2_r = r; p2_pb0 = 9 * ch;
        const float4* bp = &v4[r][p2_pb0];
        const int ay = ty0 - R + r;
        const float cy = ccnt(ay);
        const bool ayok = ((unsigned)ay < (unsigned)IMG);
        const int ax0 = tx0 - R + 8 * ch;
        if (interior) {
            if (ch < 8) p2_body<8,  true>(bp, pres, ax0, cy, ayok);
            else        p2_body<10, true>(bp, pres, ax0, cy, ayok);
        } else {
            if (ch < 8) p2_body<8,  false>(bp, pres, ax0, cy, ayok);
            else        p2_body<10, false>(bp, pres, ax0, cy, ayok);
        }
    }
    __syncthreads();   // all v4 reads drained -> safe to overwrite with ab2

    // ---- x-prefetch for P4 (2 phases ahead; L2 latency hides under P2b+P3).
    float4 xpa = make_float4(0.f, 0.f, 0.f, 0.f), xpb = xpa;
    size_t obase = 0;
    if (tid < TY * 8) {
        const int oy = tid >> 3;
        const int ch = tid & 7;
        obase = (size_t)(ty0 + oy) * IMG + tx0 + 8 * ch;
        xpa = *reinterpret_cast<const float4*>(&xp[obase]);
        xpb = *reinterpret_cast<const float4*>(&xp[obase + 4]);
    }

    // ---- P2b: write deferred A,b into ab2 (aliases v4 region). Affine.
    if (tid < 8 * AROWS) {
        float2* bw = &ab2[p2_r][p2_pb0];
#pragma unroll
        for (int i = 0; i < 8; ++i) bw[OFFD(i)] = pres[i];
    } else if (tid < 9 * AROWS) {
        float2* bw = &ab2[p2_r][p2_pb0];
#pragma unroll
        for (int i = 0; i < 10; ++i) bw[OFFD(i)] = pres[i];
    }
    __syncthreads();

    // ---- P3: vertical 11-sums of (A,b): 74 cols x 2 segs of 8 rows. Ring.
    if (tid < 2 * ACOLS) {
        const int seg = (tid >= ACOLS) ? 1 : 0;
        const int ac = tid - seg * ACOLS;
        const int r0 = seg * 8;
        const float2* rp = &ab2[r0][PB(ac)];
        float2* wp = &vab[r0][PB(ac)];
        float2 ring[10];
#pragma unroll
        for (int d = 0; d < 10; ++d) ring[d] = rp[(size_t)d * ABSTR];
        float sa = 0.f, sb = 0.f;
#pragma unroll
        for (int d = 0; d < 10; ++d) { sa += ring[d].x; sb += ring[d].y; }
#pragma unroll
        for (int s = 0; s < 8; ++s) {
            float2 lead = rp[(size_t)(10 + s) * ABSTR];
            sa += lead.x; sb += lead.y;
            if (s > 0) {
                float2 o = ring[s - 1];
                sa -= o.x; sb -= o.y;
            }
            wp[(size_t)s * ABSTR] = make_float2(sa, sb);
        }
    }
    __syncthreads();

    // ---- P4: horizontal 11-sums + epilogue. 16 rows x 8 width-8 chunks,
    // 128 threads, 8 outputs each. Affine b64 reads; prefetched x.
    if (tid < TY * 8) {
        const int oy = tid >> 3;
        const int ch = tid & 7;
        const int c0 = 8 * ch;
        const float2* vb = &vab[oy][9 * ch];   // PB(8ch) = 9ch
        float2 ring[10];
#pragma unroll
        for (int d = 0; d < 10; ++d) ring[d] = vb[OFFD(d)];
        float sa = 0.f, sb = 0.f;
#pragma unroll
        for (int d = 0; d < 10; ++d) { sa += ring[d].x; sb += ring[d].y; }
        const float xv[8] = {xpa.x, xpa.y, xpa.z, xpa.w,
                             xpb.x, xpb.y, xpb.z, xpb.w};
        float res[8];
        if (interior) {
#pragma unroll
            for (int i = 0; i < 8; ++i) {
                float2 lead = vb[OFFD(10 + i)];
                sa += lead.x; sb += lead.y;
                if (i > 0) {
                    float2 o = ring[i - 1];
                    sa -= o.x; sb -= o.y;
                }
                const float inv = 1.0f / 121.0f;
                res[i] = (sa * inv) * xv[i] + (sb * inv);
            }
        } else {
            const int gy = ty0 + oy;
            const float cy = ccnt(gy);
#pragma unroll
            for (int i = 0; i < 8; ++i) {
                float2 lead = vb[OFFD(10 + i)];
                sa += lead.x; sb += lead.y;
                if (i > 0) {
                    float2 o = ring[i - 1];
                    sa -= o.x; sb -= o.y;
                }
                float inv = __builtin_amdgcn_rcpf(cy * ccnt(tx0 + c0 + i));
                res[i] = (sa * inv) * xv[i] + (sb * inv);
            }
        }
        *reinterpret_cast<float4*>(&out[pbase + obase]) =
            make_float4(res[0], res[1], res[2], res[3]);
        *reinterpret_cast<float4*>(&out[pbase + obase + 4]) =
            make_float4(res[4], res[5], res[6], res[7]);
    }
}

extern "C" void kernel_launch(void* const* d_in, const int* in_sizes, int n_in,
                              void* d_out, int out_size, void* d_ws, size_t ws_size,
                              hipStream_t stream) {
    const float* x = (const float*)d_in[0];
    const float* y = (const float*)d_in[1];
    float* out = (float*)d_out;

    const int planes = in_sizes[0] / (IMG * IMG);  // 24

    dim3 grid(IMG / TX, IMG / TY, planes);  // 8 x 32 x 24
    guided_fused<<<grid, 256, 0, stream>>>(x, y, out);
}

// Round 5
// 120.696 us; speedup vs baseline: 1.0056x; 1.0056x over previous
//
#include <hip/hip_runtime.h>

// Guided filter r=5, B=8 C=3 H=W=512 fp32 — single fused kernel, round 12.
// TY=16 (grid 8x32x24 = 6144 blocks). All LDS accesses affine (base +
// compile-time immediate; chunk starts multiples of 8 so PB(c0+d) = PB(c0)
// + OFFD(d)).
// r12 = r10's P1 latency structure + r11's VALU reductions:
//  - P1 REVERTED to 3 segments 9/9/8 (252 thr, 19-row register window):
//    38 live load values + overhead fits the ~52-VGPR batch -> ALL loads
//    issue in ONE batch (single s_waitcnt, one HBM round-trip/thread).
//    r11's 2x13 (46 values) overflowed the batch -> serialized load chains
//    (-5.3 us regression, VALUBusy 52.6->40.3 while dur rose).
//  - KEPT from r11: static-trip p2_body<NOUT,INTR> (no runtime i<nout mask),
//    interior/boundary block-uniform splits in P2a/P4 (interior: inv=1/121
//    const, no guards), split P2b writes, column-edge fast path in P1.
// Pipeline: P1 vsums(x,y,xy,xx)->v4[26][97sw] f4 | P2a hsums+A,b->regs |
//   x-prefetch (tid<128) | P2b regs->ab2 (ALIASES v4) | P3 vsums(A,b)->vab
//   @+17,280 | P4 hsums+epilogue, 2x float4 stores.
// Bank floors (words mod 32): all phases at the multi-word access floor
// (b128: 8 words/bank, b64: 4/bank) — measured SQ_LDS_BANK_CONFLICT is
// dominated by this floor, not fixable conflicts.
// ab2 @0, vab @17,280 (=135*128). LDS 40,352 B -> 4 blocks/CU.

#define R    5
#define TX   64
#define TY   16
#define IMG  512
#define AROWS (TY + 2 * R)   // 26
#define ACOLS (TX + 2 * R)   // 74
#define XCOLS (TX + 4 * R)   // 84
#define V4STR 97             // float4 row stride
#define ABSTR 83             // float2 row stride
#define OFF_VAB 17280                            // 135*128 >= ab2's 17,264
#define SMEM_TOTAL (AROWS * V4STR * 16)          // 40,352

#define PB(c)   ((c) + ((c) >> 3))
#define OFFD(d) ((d) + ((d) >> 3))   // PB(c0+d)-PB(c0) when c0%8==0

__device__ __forceinline__ float ccnt(int g) {
    int lo = max(g - R, 0), hi = min(g + R, IMG - 1);
    return (float)(hi - lo + 1);
}

// P2a inner: horizontal 11-sum ring + A,b math. NOUT/INTR compile-time.
template <int NOUT, bool INTR>
__device__ __forceinline__ void p2_body(const float4* __restrict__ bp,
                                        float2* pres, int ax0, float cy,
                                        bool ayok) {
    float4 ring[10];
#pragma unroll
    for (int d = 0; d < 10; ++d) ring[d] = bp[OFFD(d)];
    float sx = 0.f, sy = 0.f, sxy = 0.f, sxx = 0.f;
#pragma unroll
    for (int d = 0; d < 10; ++d) {
        sx += ring[d].x; sy += ring[d].y;
        sxy += ring[d].z; sxx += ring[d].w;
    }
#pragma unroll
    for (int i = 0; i < NOUT; ++i) {
        float4 lead = bp[OFFD(10 + i)];
        sx += lead.x; sy += lead.y; sxy += lead.z; sxx += lead.w;
        if (i > 0) {
            float4 o = ring[i - 1];
            sx -= o.x; sy -= o.y; sxy -= o.z; sxx -= o.w;
        }
        float A = 0.f, bb = 0.f;
        if (INTR) {
            const float inv = 1.0f / 121.0f;
            float mx = sx * inv, my = sy * inv;
            float cov = sxy * inv - mx * my;
            float var = sxx * inv - mx * mx;
            A = cov * __builtin_amdgcn_rcpf(var + 0.01f);
            bb = my - A * mx;
        } else {
            const int ax = ax0 + i;
            if (ayok && ((unsigned)ax < (unsigned)IMG)) {
                float inv = __builtin_amdgcn_rcpf(cy * ccnt(ax));
                float mx = sx * inv, my = sy * inv;
                float cov = sxy * inv - mx * my;
                float var = sxx * inv - mx * mx;
                A = cov * __builtin_amdgcn_rcpf(var + 0.01f);
                bb = my - A * mx;
            }
        }
        pres[i] = make_float2(A, bb);
    }
}

__global__ __launch_bounds__(256, 4) void guided_fused(
        const float* __restrict__ x, const float* __restrict__ y,
        float* __restrict__ out) {
    __shared__ __align__(16) unsigned char smem[SMEM_TOTAL];
    float4 (*v4)[V4STR] = (float4(*)[V4STR])smem;
    float2 (*ab2)[ABSTR] = (float2(*)[ABSTR])smem;              // aliases v4
    float2 (*vab)[ABSTR] = (float2(*)[ABSTR])(smem + OFF_VAB);  // disjoint from ab2

    const int plane = blockIdx.z;
    const int tx0 = blockIdx.x * TX;
    const int ty0 = blockIdx.y * TY;
    const int tid = threadIdx.x;
    const size_t pbase = (size_t)plane * IMG * IMG;
    const float* xp = x + pbase;
    const float* yp = y + pbase;
    const bool interior = (tx0 >= 2 * R) && (tx0 + TX + 2 * R - 1 < IMG) &&
                          (ty0 >= 2 * R) && (ty0 + TY + 2 * R - 1 < IMG);

    // ---- P1: vertical 11-sums at 84 cols x 26 A,b-rows. 3 segs (9/9/8).
    // 19-row register window: all 38 loads issue in one batch (VGPR-sized).
    if (tid < 3 * XCOLS) {
        const int seg = tid / XCOLS;
        const int cc  = tid - seg * XCOLS;
        const int r0  = seg * 9;              // 0, 9, 18
        const int gx  = tx0 - 2 * R + cc;
        const int gy0 = ty0 - 2 * R + r0;

        float xv[19], yv[19];
        if (interior) {
            const float* xc = xp + (size_t)gy0 * IMG + gx;
            const float* yc = yp + (size_t)gy0 * IMG + gx;
#pragma unroll
            for (int j = 0; j < 19; ++j) {
                xv[j] = xc[(size_t)j * IMG];
                yv[j] = yc[(size_t)j * IMG];
            }
        } else {
            const bool xok = ((unsigned)gx < (unsigned)IMG);
            const bool rows_ok = (gy0 >= 0) && (gy0 + 18 < IMG);
            if (rows_ok) {
                if (xok) {
                    const float* xc = xp + (size_t)gy0 * IMG + gx;
                    const float* yc = yp + (size_t)gy0 * IMG + gx;
#pragma unroll
                    for (int j = 0; j < 19; ++j) {
                        xv[j] = xc[(size_t)j * IMG];
                        yv[j] = yc[(size_t)j * IMG];
                    }
                } else {
#pragma unroll
                    for (int j = 0; j < 19; ++j) { xv[j] = 0.f; yv[j] = 0.f; }
                }
            } else {
#pragma unroll
                for (int j = 0; j < 19; ++j) {
                    int gy = gy0 + j;
                    bool ok = xok && ((unsigned)gy < (unsigned)IMG);
                    size_t o = (size_t)gy * IMG + gx;
                    xv[j] = ok ? xp[o] : 0.f;
                    yv[j] = ok ? yp[o] : 0.f;
                }
            }
        }
        float sx = 0.f, sy = 0.f, sxy = 0.f, sxx = 0.f;
#pragma unroll
        for (int j = 0; j < 11; ++j) {
            sx += xv[j]; sy += yv[j];
            sxy += xv[j] * yv[j]; sxx += xv[j] * xv[j];
        }
        float4* wp = &v4[r0][PB(cc)];
        wp[0] = make_float4(sx, sy, sxy, sxx);
#pragma unroll
        for (int s = 1; s < 9; ++s) {
            if (r0 + s < AROWS) {   // seg2 stops at 8 rows
                float xn = xv[s + 10], yn = yv[s + 10];
                float xo = xv[s - 1],  yo = yv[s - 1];
                sx  += xn - xo;
                sy  += yn - yo;
                sxy += xn * yn - xo * yo;
                sxx += xn * xn - xo * xo;
                wp[(size_t)s * V4STR] = make_float4(sx, sy, sxy, sxx);
            }
        }
    }
    __syncthreads();

    // ---- P2a: horizontal 11-sums -> A,b on 74x26, DEFERRED to registers.
    // 234 threads: chunk ch = tid/26 (0..8), row r = tid%26, c0 = 8ch.
    // Static-trip loops: ch<8 width 8, ch==8 width 10 (cols 64..73).
    int p2_r = 0, p2_pb0 = 0;
    float2 pres[10];
    if (tid < 9 * AROWS) {
        const int ch = tid / AROWS;
        const int r  = tid - ch * AROWS;
        p2_r = r; p2_pb0 = 9 * ch;
        const float4* bp = &v4[r][p2_pb0];
        const int ay = ty0 - R + r;
        const float cy = ccnt(ay);
        const bool ayok = ((unsigned)ay < (unsigned)IMG);
        const int ax0 = tx0 - R + 8 * ch;
        if (interior) {
            if (ch < 8) p2_body<8,  true>(bp, pres, ax0, cy, ayok);
            else        p2_body<10, true>(bp, pres, ax0, cy, ayok);
        } else {
            if (ch < 8) p2_body<8,  false>(bp, pres, ax0, cy, ayok);
            else        p2_body<10, false>(bp, pres, ax0, cy, ayok);
        }
    }
    __syncthreads();   // all v4 reads drained -> safe to overwrite with ab2

    // ---- x-prefetch for P4 (2 phases ahead; L2 latency hides under P2b+P3).
    float4 xpa = make_float4(0.f, 0.f, 0.f, 0.f), xpb = xpa;
    size_t obase = 0;
    if (tid < TY * 8) {
        const int oy = tid >> 3;
        const int ch = tid & 7;
        obase = (size_t)(ty0 + oy) * IMG + tx0 + 8 * ch;
        xpa = *reinterpret_cast<const float4*>(&xp[obase]);
        xpb = *reinterpret_cast<const float4*>(&xp[obase + 4]);
    }

    // ---- P2b: write deferred A,b into ab2 (aliases v4 region). Affine.
    if (tid < 8 * AROWS) {
        float2* bw = &ab2[p2_r][p2_pb0];
#pragma unroll
        for (int i = 0; i < 8; ++i) bw[OFFD(i)] = pres[i];
    } else if (tid < 9 * AROWS) {
        float2* bw = &ab2[p2_r][p2_pb0];
#pragma unroll
        for (int i = 0; i < 10; ++i) bw[OFFD(i)] = pres[i];
    }
    __syncthreads();

    // ---- P3: vertical 11-sums of (A,b): 74 cols x 2 segs of 8 rows. Ring.
    if (tid < 2 * ACOLS) {
        const int seg = (tid >= ACOLS) ? 1 : 0;
        const int ac = tid - seg * ACOLS;
        const int r0 = seg * 8;
        const float2* rp = &ab2[r0][PB(ac)];
        float2* wp = &vab[r0][PB(ac)];
        float2 ring[10];
#pragma unroll
        for (int d = 0; d < 10; ++d) ring[d] = rp[(size_t)d * ABSTR];
        float sa = 0.f, sb = 0.f;
#pragma unroll
        for (int d = 0; d < 10; ++d) { sa += ring[d].x; sb += ring[d].y; }
#pragma unroll
        for (int s = 0; s < 8; ++s) {
            float2 lead = rp[(size_t)(10 + s) * ABSTR];
            sa += lead.x; sb += lead.y;
            if (s > 0) {
                float2 o = ring[s - 1];
                sa -= o.x; sb -= o.y;
            }
            wp[(size_t)s * ABSTR] = make_float2(sa, sb);
        }
    }
    __syncthreads();

    // ---- P4: horizontal 11-sums + epilogue. 16 rows x 8 width-8 chunks,
    // 128 threads, 8 outputs each. Affine b64 reads; prefetched x.
    if (tid < TY * 8) {
        const int oy = tid >> 3;
        const int ch = tid & 7;
        const int c0 = 8 * ch;
        const float2* vb = &vab[oy][9 * ch];   // PB(8ch) = 9ch
        float2 ring[10];
#pragma unroll
        for (int d = 0; d < 10; ++d) ring[d] = vb[OFFD(d)];
        float sa = 0.f, sb = 0.f;
#pragma unroll
        for (int d = 0; d < 10; ++d) { sa += ring[d].x; sb += ring[d].y; }
        const float xv[8] = {xpa.x, xpa.y, xpa.z, xpa.w,
                             xpb.x, xpb.y, xpb.z, xpb.w};
        float res[8];
        if (interior) {
#pragma unroll
            for (int i = 0; i < 8; ++i) {
                float2 lead = vb[OFFD(10 + i)];
                sa += lead.x; sb += lead.y;
                if (i > 0) {
                    float2 o = ring[i - 1];
                    sa -= o.x; sb -= o.y;
                }
                const float inv = 1.0f / 121.0f;
                res[i] = (sa * inv) * xv[i] + (sb * inv);
            }
        } else {
            const int gy = ty0 + oy;
            const float cy = ccnt(gy);
#pragma unroll
            for (int i = 0; i < 8; ++i) {
                float2 lead = vb[OFFD(10 + i)];
                sa += lead.x; sb += lead.y;
                if (i > 0) {
                    float2 o = ring[i - 1];
                    sa -= o.x; sb -= o.y;
                }
                float inv = __builtin_amdgcn_rcpf(cy * ccnt(tx0 + c0 + i));
                res[i] = (sa * inv) * xv[i] + (sb * inv);
            }
        }
        *reinterpret_cast<float4*>(&out[pbase + obase]) =
            make_float4(res[0], res[1], res[2], res[3]);
        *reinterpret_cast<float4*>(&out[pbase + obase + 4]) =
            make_float4(res[4], res[5], res[6], res[7]);
    }
}

extern "C" void kernel_launch(void* const* d_in, const int* in_sizes, int n_in,
                              void* d_out, int out_size, void* d_ws, size_t ws_size,
                              hipStream_t stream) {
    const float* x = (const float*)d_in[0];
    const float* y = (const float*)d_in[1];
    float* out = (float*)d_out;

    const int planes = in_sizes[0] / (IMG * IMG);  // 24

    dim3 grid(IMG / TX, IMG / TY, planes);  // 8 x 32 x 24
    guided_fused<<<grid, 256, 0, stream>>>(x, y, out);
}

// Round 7
// 116.571 us; speedup vs baseline: 1.0412x; 1.0354x over previous
//
#include <hip/hip_runtime.h>

// Guided filter r=5, B=8 C=3 H=W=512 fp32 — single fused kernel, round 13.
// TY=16 (grid 8x32x24 = 6144 blocks). All LDS accesses affine (base +
// compile-time immediate; chunk starts multiples of 8 so PB(c0+d) = PB(c0)
// + OFFD(d)).
// r13 = r12 minus INTRA-WAVE DIVERGENT code duplication:
//  - P2a/P2b: single body with runtime `i < nout` mask (r10's proven form).
//    r11/r12's `if (ch<8) body<8> else body<10>` put ch=7 and ch=8 threads
//    in the same wave -> both ~90-VALU unrolled bodies executed serially
//    under exec masks -> wave-3 straggler, whole block waits at barrier
//    (+3.5 us r10->r12). Template retained ONLY on INTR (block-uniform).
//  - P1: 3 segments 9/9/8 (252 thr, 19-row window = 38 loads in ONE VGPR
//    batch; r11's 2x13/46-load variant overflowed 52 VGPR -> serialized).
//  - Block-uniform splits kept: P2a/P4 interior (inv=1/121, no guards),
//    P1 boundary fast paths.
// Pipeline: P1 vsums(x,y,xy,xx)->v4[26][97sw] f4 | P2a hsums+A,b->regs |
//   x-prefetch (tid<128) | P2b regs->ab2 (ALIASES v4) | P3 vsums(A,b)->vab
//   @+17,280 | P4 hsums+epilogue, 2x float4 stores.
// Bank floors (words mod 32): all phases at the multi-word access floor
// (b128: 8 words/bank, b64: 4/bank) — measured SQ_LDS_BANK_CONFLICT is
// dominated by this floor, not fixable conflicts.
// ab2 @0, vab @17,280 (=135*128). LDS 40,352 B -> 4 blocks/CU.

#define R    5
#define TX   64
#define TY   16
#define IMG  512
#define AROWS (TY + 2 * R)   // 26
#define ACOLS (TX + 2 * R)   // 74
#define XCOLS (TX + 4 * R)   // 84
#define V4STR 97             // float4 row stride
#define ABSTR 83             // float2 row stride
#define OFF_VAB 17280                            // 135*128 >= ab2's 17,264
#define SMEM_TOTAL (AROWS * V4STR * 16)          // 40,352

#define PB(c)   ((c) + ((c) >> 3))
#define OFFD(d) ((d) + ((d) >> 3))   // PB(c0+d)-PB(c0) when c0%8==0

__device__ __forceinline__ float ccnt(int g) {
    int lo = max(g - R, 0), hi = min(g + R, IMG - 1);
    return (float)(hi - lo + 1);
}

// P2a inner: horizontal 11-sum ring + A,b math. Single body, runtime nout
// (per-lane mask — NO divergent body duplication). INTR is block-uniform.
template <bool INTR>
__device__ __forceinline__ void p2_body(const float4* __restrict__ bp,
                                        float2* pres, int nout, int ax0,
                                        float cy, bool ayok) {
    float4 ring[10];
#pragma unroll
    for (int d = 0; d < 10; ++d) ring[d] = bp[OFFD(d)];
    float sx = 0.f, sy = 0.f, sxy = 0.f, sxx = 0.f;
#pragma unroll
    for (int d = 0; d < 10; ++d) {
        sx += ring[d].x; sy += ring[d].y;
        sxy += ring[d].z; sxx += ring[d].w;
    }
#pragma unroll
    for (int i = 0; i < 10; ++i) {
        if (i < nout) {
            float4 lead = bp[OFFD(10 + i)];
            sx += lead.x; sy += lead.y; sxy += lead.z; sxx += lead.w;
            if (i > 0) {
                float4 o = ring[i - 1];
                sx -= o.x; sy -= o.y; sxy -= o.z; sxx -= o.w;
            }
            float A = 0.f, bb = 0.f;
            if (INTR) {
                const float inv = 1.0f / 121.0f;
                float mx = sx * inv, my = sy * inv;
                float cov = sxy * inv - mx * my;
                float var = sxx * inv - mx * mx;
                A = cov * __builtin_amdgcn_rcpf(var + 0.01f);
                bb = my - A * mx;
            } else {
                const int ax = ax0 + i;
                if (ayok && ((unsigned)ax < (unsigned)IMG)) {
                    float inv = __builtin_amdgcn_rcpf(cy * ccnt(ax));
                    float mx = sx * inv, my = sy * inv;
                    float cov = sxy * inv - mx * my;
                    float var = sxx * inv - mx * mx;
                    A = cov * __builtin_amdgcn_rcpf(var + 0.01f);
                    bb = my - A * mx;
                }
            }
            pres[i] = make_float2(A, bb);
        }
    }
}

__global__ __launch_bounds__(256, 4) void guided_fused(
        const float* __restrict__ x, const float* __restrict__ y,
        float* __restrict__ out) {
    __shared__ __align__(16) unsigned char smem[SMEM_TOTAL];
    float4 (*v4)[V4STR] = (float4(*)[V4STR])smem;
    float2 (*ab2)[ABSTR] = (float2(*)[ABSTR])smem;              // aliases v4
    float2 (*vab)[ABSTR] = (float2(*)[ABSTR])(smem + OFF_VAB);  // disjoint from ab2

    const int plane = blockIdx.z;
    const int tx0 = blockIdx.x * TX;
    const int ty0 = blockIdx.y * TY;
    const int tid = threadIdx.x;
    const size_t pbase = (size_t)plane * IMG * IMG;
    const float* xp = x + pbase;
    const float* yp = y + pbase;
    const bool interior = (tx0 >= 2 * R) && (tx0 + TX + 2 * R - 1 < IMG) &&
                          (ty0 >= 2 * R) && (ty0 + TY + 2 * R - 1 < IMG);

    // ---- P1: vertical 11-sums at 84 cols x 26 A,b-rows. 3 segs (9/9/8).
    // 19-row register window: all 38 loads issue in one batch (VGPR-sized).
    if (tid < 3 * XCOLS) {
        const int seg = tid / XCOLS;
        const int cc  = tid - seg * XCOLS;
        const int r0  = seg * 9;              // 0, 9, 18
        const int gx  = tx0 - 2 * R + cc;
        const int gy0 = ty0 - 2 * R + r0;

        float xv[19], yv[19];
        if (interior) {
            const float* xc = xp + (size_t)gy0 * IMG + gx;
            const float* yc = yp + (size_t)gy0 * IMG + gx;
#pragma unroll
            for (int j = 0; j < 19; ++j) {
                xv[j] = xc[(size_t)j * IMG];
                yv[j] = yc[(size_t)j * IMG];
            }
        } else {
            const bool xok = ((unsigned)gx < (unsigned)IMG);
            const bool rows_ok = (gy0 >= 0) && (gy0 + 18 < IMG);
            if (rows_ok) {
                if (xok) {
                    const float* xc = xp + (size_t)gy0 * IMG + gx;
                    const float* yc = yp + (size_t)gy0 * IMG + gx;
#pragma unroll
                    for (int j = 0; j < 19; ++j) {
                        xv[j] = xc[(size_t)j * IMG];
                        yv[j] = yc[(size_t)j * IMG];
                    }
                } else {
#pragma unroll
                    for (int j = 0; j < 19; ++j) { xv[j] = 0.f; yv[j] = 0.f; }
                }
            } else {
#pragma unroll
                for (int j = 0; j < 19; ++j) {
                    int gy = gy0 + j;
                    bool ok = xok && ((unsigned)gy < (unsigned)IMG);
                    size_t o = (size_t)gy * IMG + gx;
                    xv[j] = ok ? xp[o] : 0.f;
                    yv[j] = ok ? yp[o] : 0.f;
                }
            }
        }
        float sx = 0.f, sy = 0.f, sxy = 0.f, sxx = 0.f;
#pragma unroll
        for (int j = 0; j < 11; ++j) {
            sx += xv[j]; sy += yv[j];
            sxy += xv[j] * yv[j]; sxx += xv[j] * xv[j];
        }
        float4* wp = &v4[r0][PB(cc)];
        wp[0] = make_float4(sx, sy, sxy, sxx);
#pragma unroll
        for (int s = 1; s < 9; ++s) {
            if (r0 + s < AROWS) {   // seg2 stops at 8 rows
                float xn = xv[s + 10], yn = yv[s + 10];
                float xo = xv[s - 1],  yo = yv[s - 1];
                sx  += xn - xo;
                sy  += yn - yo;
                sxy += xn * yn - xo * yo;
                sxx += xn * xn - xo * xo;
                wp[(size_t)s * V4STR] = make_float4(sx, sy, sxy, sxx);
            }
        }
    }
    __syncthreads();

    // ---- P2a: horizontal 11-sums -> A,b on 74x26, DEFERRED to registers.
    // 234 threads: chunk ch = tid/26 (0..8), row r = tid%26, c0 = 8ch.
    // Runtime nout (8, or 10 for ch=8) masked per-lane inside ONE body.
    int p2_r = 0, p2_pb0 = 0, p2_nout = 0;
    float2 pres[10];
    if (tid < 9 * AROWS) {
        const int ch = tid / AROWS;
        const int r  = tid - ch * AROWS;
        const int nout = (ch == 8) ? 10 : 8;
        p2_r = r; p2_pb0 = 9 * ch; p2_nout = nout;
        const float4* bp = &v4[r][p2_pb0];
        const int ay = ty0 - R + r;
        const float cy = ccnt(ay);
        const bool ayok = ((unsigned)ay < (unsigned)IMG);
        const int ax0 = tx0 - R + 8 * ch;
        if (interior) p2_body<true >(bp, pres, nout, ax0, cy, ayok);
        else          p2_body<false>(bp, pres, nout, ax0, cy, ayok);
    }
    __syncthreads();   // all v4 reads drained -> safe to overwrite with ab2

    // ---- x-prefetch for P4 (2 phases ahead; L2 latency hides under P2b+P3).
    float4 xpa = make_float4(0.f, 0.f, 0.f, 0.f), xpb = xpa;
    size_t obase = 0;
    if (tid < TY * 8) {
        const int oy = tid >> 3;
        const int ch = tid & 7;
        obase = (size_t)(ty0 + oy) * IMG + tx0 + 8 * ch;
        xpa = *reinterpret_cast<const float4*>(&xp[obase]);
        xpb = *reinterpret_cast<const float4*>(&xp[obase + 4]);
    }

    // ---- P2b: write deferred A,b into ab2 (aliases v4 region). Affine,
    // single loop with runtime mask (no divergent duplication).
    if (tid < 9 * AROWS) {
        float2* bw = &ab2[p2_r][p2_pb0];
#pragma unroll
        for (int i = 0; i < 10; ++i) {
            if (i < p2_nout) bw[OFFD(i)] = pres[i];
        }
    }
    __syncthreads();

    // ---- P3: vertical 11-sums of (A,b): 74 cols x 2 segs of 8 rows. Ring.
    if (tid < 2 * ACOLS) {
        const int seg = (tid >= ACOLS) ? 1 : 0;
        const int ac = tid - seg * ACOLS;
        const int r0 = seg * 8;
        const float2* rp = &ab2[r0][PB(ac)];
        float2* wp = &vab[r0][PB(ac)];
        float2 ring[10];
#pragma unroll
        for (int d = 0; d < 10; ++d) ring[d] = rp[(size_t)d * ABSTR];
        float sa = 0.f, sb = 0.f;
#pragma unroll
        for (int d = 0; d < 10; ++d) { sa += ring[d].x; sb += ring[d].y; }
#pragma unroll
        for (int s = 0; s < 8; ++s) {
            float2 lead = rp[(size_t)(10 + s) * ABSTR];
            sa += lead.x; sb += lead.y;
            if (s > 0) {
                float2 o = ring[s - 1];
                sa -= o.x; sb -= o.y;
            }
            wp[(size_t)s * ABSTR] = make_float2(sa, sb);
        }
    }
    __syncthreads();

    // ---- P4: horizontal 11-sums + epilogue. 16 rows x 8 width-8 chunks,
    // 128 threads, 8 outputs each. Affine b64 reads; prefetched x.
    if (tid < TY * 8) {
        const int oy = tid >> 3;
        const int ch = tid & 7;
        const int c0 = 8 * ch;
        const float2* vb = &vab[oy][9 * ch];   // PB(8ch) = 9ch
        float2 ring[10];
#pragma unroll
        for (int d = 0; d < 10; ++d) ring[d] = vb[OFFD(d)];
        float sa = 0.f, sb = 0.f;
#pragma unroll
        for (int d = 0; d < 10; ++d) { sa += ring[d].x; sb += ring[d].y; }
        const float xv[8] = {xpa.x, xpa.y, xpa.z, xpa.w,
                             xpb.x, xpb.y, xpb.z, xpb.w};
        float res[8];
        if (interior) {
#pragma unroll
            for (int i = 0; i < 8; ++i) {
                float2 lead = vb[OFFD(10 + i)];
                sa += lead.x; sb += lead.y;
                if (i > 0) {
                    float2 o = ring[i - 1];
                    sa -= o.x; sb -= o.y;
                }
                const float inv = 1.0f / 121.0f;
                res[i] = (sa * inv) * xv[i] + (sb * inv);
            }
        } else {
            const int gy = ty0 + oy;
            const float cy = ccnt(gy);
#pragma unroll
            for (int i = 0; i < 8; ++i) {
                float2 lead = vb[OFFD(10 + i)];
                sa += lead.x; sb += lead.y;
                if (i > 0) {
                    float2 o = ring[i - 1];
                    sa -= o.x; sb -= o.y;
                }
                float inv = __builtin_amdgcn_rcpf(cy * ccnt(tx0 + c0 + i));
                res[i] = (sa * inv) * xv[i] + (sb * inv);
            }
        }
        *reinterpret_cast<float4*>(&out[pbase + obase]) =
            make_float4(res[0], res[1], res[2], res[3]);
        *reinterpret_cast<float4*>(&out[pbase + obase + 4]) =
            make_float4(res[4], res[5], res[6], res[7]);
    }
}

extern "C" void kernel_launch(void* const* d_in, const int* in_sizes, int n_in,
                              void* d_out, int out_size, void* d_ws, size_t ws_size,
                              hipStream_t stream) {
    const float* x = (const float*)d_in[0];
    const float* y = (const float*)d_in[1];
    float* out = (float*)d_out;

    const int planes = in_sizes[0] / (IMG * IMG);  // 24

    dim3 grid(IMG / TX, IMG / TY, planes);  // 8 x 32 x 24
    guided_fused<<<grid, 256, 0, stream>>>(x, y, out);
}

// Round 8
// 115.795 us; speedup vs baseline: 1.0481x; 1.0067x over previous
//
#include <hip/hip_runtime.h>

// Guided filter r=5, B=8 C=3 H=W=512 fp32 — single fused kernel, round 14.
// TY=16 (grid 8x32x24 = 6144 blocks). All LDS accesses affine.
// r14 = r13 + two wave-balance/VALU cuts (layouts/numerics unchanged):
//  - P4 on 256 threads: each width-8 chunk split across a thread PAIR
//    (t: outputs 0-3 from ring cols d=0..13; t+128: outputs 4-7 from
//    d=4..17). Branch on tid<128 is WAVE-UNIFORM (split at wave boundary)
//    -> no intra-wave body duplication (r12 lesson). Per-wave LDS reads
//    18->14, per-wave VALU ~120->~50, all 4 SIMDs active in final phase.
//    x-prefetch + store: ONE float4 per thread.
//  - P1 trailing-product stash: pxy[8]/pxx[8] saved during prime (muls
//    CSE'd, zero extra), update rows reuse instead of re-multiplying
//    xo*yo / xo*xo: -16 mul/thread in the largest phase. VGPR ~52->68.
//  - KEPT from r13: single P2a/P2b body with runtime i<nout mask (no
//    divergent duplication); P1 3 segs 9/9/8 (38-load single batch);
//    block-uniform INTR splits.
// Pipeline: P1 vsums(x,y,xy,xx)->v4[26][97sw] f4 | P2a hsums+A,b->regs |
//   x-prefetch (256 thr) | P2b regs->ab2 (ALIASES v4) | P3 vsums(A,b)->vab
//   @+17,280 | P4 hsums+epilogue (256 thr), 1x float4 store/thread.
// Bank floors (words mod 32): all phases at the multi-word access floor
// (b128: 8 words/bank, b64: 4/bank); P4's pair-split read pattern
// (6*oy + 18*ch + const) spreads ~2 words/bank -> free.
// ab2 @0, vab @17,280 (=135*128). LDS 40,352 B -> 4 blocks/CU.

#define R    5
#define TX   64
#define TY   16
#define IMG  512
#define AROWS (TY + 2 * R)   // 26
#define ACOLS (TX + 2 * R)   // 74
#define XCOLS (TX + 4 * R)   // 84
#define V4STR 97             // float4 row stride
#define ABSTR 83             // float2 row stride
#define OFF_VAB 17280                            // 135*128 >= ab2's 17,264
#define SMEM_TOTAL (AROWS * V4STR * 16)          // 40,352

#define PB(c)   ((c) + ((c) >> 3))
#define OFFD(d) ((d) + ((d) >> 3))   // PB(c0+d)-PB(c0) when c0%8==0

__device__ __forceinline__ float ccnt(int g) {
    int lo = max(g - R, 0), hi = min(g + R, IMG - 1);
    return (float)(hi - lo + 1);
}

// P2a inner: horizontal 11-sum ring + A,b math. Single body, runtime nout
// (per-lane mask — NO divergent body duplication). INTR is block-uniform.
template <bool INTR>
__device__ __forceinline__ void p2_body(const float4* __restrict__ bp,
                                        float2* pres, int nout, int ax0,
                                        float cy, bool ayok) {
    float4 ring[10];
#pragma unroll
    for (int d = 0; d < 10; ++d) ring[d] = bp[OFFD(d)];
    float sx = 0.f, sy = 0.f, sxy = 0.f, sxx = 0.f;
#pragma unroll
    for (int d = 0; d < 10; ++d) {
        sx += ring[d].x; sy += ring[d].y;
        sxy += ring[d].z; sxx += ring[d].w;
    }
#pragma unroll
    for (int i = 0; i < 10; ++i) {
        if (i < nout) {
            float4 lead = bp[OFFD(10 + i)];
            sx += lead.x; sy += lead.y; sxy += lead.z; sxx += lead.w;
            if (i > 0) {
                float4 o = ring[i - 1];
                sx -= o.x; sy -= o.y; sxy -= o.z; sxx -= o.w;
            }
            float A = 0.f, bb = 0.f;
            if (INTR) {
                const float inv = 1.0f / 121.0f;
                float mx = sx * inv, my = sy * inv;
                float cov = sxy * inv - mx * my;
                float var = sxx * inv - mx * mx;
                A = cov * __builtin_amdgcn_rcpf(var + 0.01f);
                bb = my - A * mx;
            } else {
                const int ax = ax0 + i;
                if (ayok && ((unsigned)ax < (unsigned)IMG)) {
                    float inv = __builtin_amdgcn_rcpf(cy * ccnt(ax));
                    float mx = sx * inv, my = sy * inv;
                    float cov = sxy * inv - mx * my;
                    float var = sxx * inv - mx * mx;
                    A = cov * __builtin_amdgcn_rcpf(var + 0.01f);
                    bb = my - A * mx;
                }
            }
            pres[i] = make_float2(A, bb);
        }
    }
}

// P4 half: 4 outputs (cols c0+H .. c0+H+3), ring cols d = H..H+13.
// H is a template const so all LDS offsets stay compile-time immediates.
template <int H, bool INTR>
__device__ __forceinline__ void p4_half(const float2* __restrict__ vb,
                                        const float4 xv4, float res[4],
                                        int gx0, float cy) {
    float2 ring[10];
#pragma unroll
    for (int d = 0; d < 10; ++d) ring[d] = vb[OFFD(H + d)];
    float sa = 0.f, sb = 0.f;
#pragma unroll
    for (int d = 0; d < 10; ++d) { sa += ring[d].x; sb += ring[d].y; }
    const float xv[4] = {xv4.x, xv4.y, xv4.z, xv4.w};
#pragma unroll
    for (int i = 0; i < 4; ++i) {
        float2 lead = vb[OFFD(H + 10 + i)];
        sa += lead.x; sb += lead.y;
        if (i > 0) {
            float2 o = ring[i - 1];
            sa -= o.x; sb -= o.y;
        }
        float inv;
        if (INTR) inv = 1.0f / 121.0f;
        else      inv = __builtin_amdgcn_rcpf(cy * ccnt(gx0 + i));
        res[i] = (sa * inv) * xv[i] + (sb * inv);
    }
}

__global__ __launch_bounds__(256, 4) void guided_fused(
        const float* __restrict__ x, const float* __restrict__ y,
        float* __restrict__ out) {
    __shared__ __align__(16) unsigned char smem[SMEM_TOTAL];
    float4 (*v4)[V4STR] = (float4(*)[V4STR])smem;
    float2 (*ab2)[ABSTR] = (float2(*)[ABSTR])smem;              // aliases v4
    float2 (*vab)[ABSTR] = (float2(*)[ABSTR])(smem + OFF_VAB);  // disjoint from ab2

    const int plane = blockIdx.z;
    const int tx0 = blockIdx.x * TX;
    const int ty0 = blockIdx.y * TY;
    const int tid = threadIdx.x;
    const size_t pbase = (size_t)plane * IMG * IMG;
    const float* xp = x + pbase;
    const float* yp = y + pbase;
    const bool interior = (tx0 >= 2 * R) && (tx0 + TX + 2 * R - 1 < IMG) &&
                          (ty0 >= 2 * R) && (ty0 + TY + 2 * R - 1 < IMG);

    // ---- P1: vertical 11-sums at 84 cols x 26 A,b-rows. 3 segs (9/9/8).
    // 19-row register window: all 38 loads issue in one batch (VGPR-sized).
    if (tid < 3 * XCOLS) {
        const int seg = tid / XCOLS;
        const int cc  = tid - seg * XCOLS;
        const int r0  = seg * 9;              // 0, 9, 18
        const int gx  = tx0 - 2 * R + cc;
        const int gy0 = ty0 - 2 * R + r0;

        float xv[19], yv[19];
        if (interior) {
            const float* xc = xp + (size_t)gy0 * IMG + gx;
            const float* yc = yp + (size_t)gy0 * IMG + gx;
#pragma unroll
            for (int j = 0; j < 19; ++j) {
                xv[j] = xc[(size_t)j * IMG];
                yv[j] = yc[(size_t)j * IMG];
            }
        } else {
            const bool xok = ((unsigned)gx < (unsigned)IMG);
            const bool rows_ok = (gy0 >= 0) && (gy0 + 18 < IMG);
            if (rows_ok) {
                if (xok) {
                    const float* xc = xp + (size_t)gy0 * IMG + gx;
                    const float* yc = yp + (size_t)gy0 * IMG + gx;
#pragma unroll
                    for (int j = 0; j < 19; ++j) {
                        xv[j] = xc[(size_t)j * IMG];
                        yv[j] = yc[(size_t)j * IMG];
                    }
                } else {
#pragma unroll
                    for (int j = 0; j < 19; ++j) { xv[j] = 0.f; yv[j] = 0.f; }
                }
            } else {
#pragma unroll
                for (int j = 0; j < 19; ++j) {
                    int gy = gy0 + j;
                    bool ok = xok && ((unsigned)gy < (unsigned)IMG);
                    size_t o = (size_t)gy * IMG + gx;
                    xv[j] = ok ? xp[o] : 0.f;
                    yv[j] = ok ? yp[o] : 0.f;
                }
            }
        }
        float sx = 0.f, sy = 0.f, sxy = 0.f, sxx = 0.f;
        float pxy[8], pxx[8];   // trailing-edge product stash (rows 0..7)
#pragma unroll
        for (int j = 0; j < 11; ++j) {
            float mxy = xv[j] * yv[j];
            float mxx = xv[j] * xv[j];
            sx += xv[j]; sy += yv[j];
            sxy += mxy; sxx += mxx;
            if (j < 8) { pxy[j] = mxy; pxx[j] = mxx; }
        }
        float4* wp = &v4[r0][PB(cc)];
        wp[0] = make_float4(sx, sy, sxy, sxx);
#pragma unroll
        for (int s = 1; s < 9; ++s) {
            if (r0 + s < AROWS) {   // seg2 stops at 8 rows
                float xn = xv[s + 10], yn = yv[s + 10];
                sx  += xn - xv[s - 1];
                sy  += yn - yv[s - 1];
                sxy += xn * yn - pxy[s - 1];
                sxx += xn * xn - pxx[s - 1];
                wp[(size_t)s * V4STR] = make_float4(sx, sy, sxy, sxx);
            }
        }
    }
    __syncthreads();

    // ---- P2a: horizontal 11-sums -> A,b on 74x26, DEFERRED to registers.
    // 234 threads: chunk ch = tid/26 (0..8), row r = tid%26, c0 = 8ch.
    // Runtime nout (8, or 10 for ch=8) masked per-lane inside ONE body.
    int p2_r = 0, p2_pb0 = 0, p2_nout = 0;
    float2 pres[10];
    if (tid < 9 * AROWS) {
        const int ch = tid / AROWS;
        const int r  = tid - ch * AROWS;
        const int nout = (ch == 8) ? 10 : 8;
        p2_r = r; p2_pb0 = 9 * ch; p2_nout = nout;
        const float4* bp = &v4[r][p2_pb0];
        const int ay = ty0 - R + r;
        const float cy = ccnt(ay);
        const bool ayok = ((unsigned)ay < (unsigned)IMG);
        const int ax0 = tx0 - R + 8 * ch;
        if (interior) p2_body<true >(bp, pres, nout, ax0, cy, ayok);
        else          p2_body<false>(bp, pres, nout, ax0, cy, ayok);
    }
    __syncthreads();   // all v4 reads drained -> safe to overwrite with ab2

    // ---- x-prefetch for P4 (2 phases ahead; L2 latency hides under P2b+P3).
    // 256 threads, ONE float4 each: thread t (t<128) covers chunk cols 0-3,
    // thread t+128 covers cols 4-7 of the same chunk.
    const int p4t  = tid & 127;
    const int p4oy = p4t >> 3;
    const int p4ch = p4t & 7;
    const int p4h  = (tid >> 7) * 4;      // 0 or 4, wave-uniform
    const size_t obase =
        (size_t)(ty0 + p4oy) * IMG + tx0 + 8 * p4ch + p4h;
    const float4 xv4 = *reinterpret_cast<const float4*>(&xp[obase]);

    // ---- P2b: write deferred A,b into ab2 (aliases v4 region). Affine,
    // single loop with runtime mask (no divergent duplication).
    if (tid < 9 * AROWS) {
        float2* bw = &ab2[p2_r][p2_pb0];
#pragma unroll
        for (int i = 0; i < 10; ++i) {
            if (i < p2_nout) bw[OFFD(i)] = pres[i];
        }
    }
    __syncthreads();

    // ---- P3: vertical 11-sums of (A,b): 74 cols x 2 segs of 8 rows. Ring.
    if (tid < 2 * ACOLS) {
        const int seg = (tid >= ACOLS) ? 1 : 0;
        const int ac = tid - seg * ACOLS;
        const int r0 = seg * 8;
        const float2* rp = &ab2[r0][PB(ac)];
        float2* wp = &vab[r0][PB(ac)];
        float2 ring[10];
#pragma unroll
        for (int d = 0; d < 10; ++d) ring[d] = rp[(size_t)d * ABSTR];
        float sa = 0.f, sb = 0.f;
#pragma unroll
        for (int d = 0; d < 10; ++d) { sa += ring[d].x; sb += ring[d].y; }
#pragma unroll
        for (int s = 0; s < 8; ++s) {
            float2 lead = rp[(size_t)(10 + s) * ABSTR];
            sa += lead.x; sb += lead.y;
            if (s > 0) {
                float2 o = ring[s - 1];
                sa -= o.x; sb -= o.y;
            }
            wp[(size_t)s * ABSTR] = make_float2(sa, sb);
        }
    }
    __syncthreads();

    // ---- P4: horizontal 11-sums + epilogue. 256 threads: 16 rows x 8
    // chunks x 2 halves. Wave-uniform tid<128 split (waves 0-1: outputs
    // 0-3; waves 2-3: outputs 4-7). Affine b64 reads; prefetched x;
    // 1x float4 store per thread.
    {
        const float2* vb = &vab[p4oy][9 * p4ch];   // PB(8ch) = 9ch
        const int gy = ty0 + p4oy;
        const int gx0 = tx0 + 8 * p4ch + p4h;
        float res[4];
        if (tid < 128) {
            if (interior) p4_half<0, true >(vb, xv4, res, gx0, 0.f);
            else          p4_half<0, false>(vb, xv4, res, gx0, ccnt(gy));
        } else {
            if (interior) p4_half<4, true >(vb, xv4, res, gx0, 0.f);
            else          p4_half<4, false>(vb, xv4, res, gx0, ccnt(gy));
        }
        *reinterpret_cast<float4*>(&out[pbase + obase]) =
            make_float4(res[0], res[1], res[2], res[3]);
    }
}

extern "C" void kernel_launch(void* const* d_in, const int* in_sizes, int n_in,
                              void* d_out, int out_size, void* d_ws, size_t ws_size,
                              hipStream_t stream) {
    const float* x = (const float*)d_in[0];
    const float* y = (const float*)d_in[1];
    float* out = (float*)d_out;

    const int planes = in_sizes[0] / (IMG * IMG);  // 24

    dim3 grid(IMG / TX, IMG / TY, planes);  // 8 x 32 x 24
    guided_fused<<<grid, 256, 0, stream>>>(x, y, out);
}